// Round 2
// baseline (666.065 us; speedup 1.0000x reference)
//
#include <hip/hip_runtime.h>
#include <math.h>

constexpr int B_ = 4, S_ = 1024, H_ = 256, NH_ = 4, NE_ = 4, D_ = 64;
constexpr float EPS_ = 1e-8f;

// XOR swizzle: spreads stride-4-row column accesses over 8 banks; preserves float4 alignment
__device__ __forceinline__ int swz(int row, int col){ return col ^ (((row>>2)&7)<<2); }

// ---- K1: sx[b,n,s,d] = x[b,s,:] . hl_w[n,d,:] + hl_b[n,d] ----
__global__ __launch_bounds__(256) void k_sx(const float* __restrict__ x, const float* __restrict__ hlw,
                                            const float* __restrict__ hlb, float* __restrict__ sx){
  int blk = blockIdx.x; int b = blk>>10, s = blk&1023;
  int tid = threadIdx.x, n = tid>>6, d = tid&63;
  __shared__ float xr[H_];
  xr[tid] = x[(size_t)blk*H_ + tid];
  __syncthreads();
  const float* wr = hlw + (size_t)(n*D_+d)*H_;
  float acc = hlb[n*D_+d];
  #pragma unroll
  for(int h=0;h<H_;h+=4){
    float4 w = *(const float4*)(wr+h);
    acc += w.x*xr[h] + w.y*xr[h+1] + w.z*xr[h+2] + w.w*xr[h+3];
  }
  sx[((size_t)(b*NH_+n)*S_+s)*D_ + d] = acc;
}

// ---- K2: q,k,v projections ----
__global__ __launch_bounds__(384) void k_qkv(const float* __restrict__ sx, const float* __restrict__ wq,
            const float* __restrict__ wk, const float* __restrict__ wv,
            float* __restrict__ q, float* __restrict__ kb, float* __restrict__ vb){
  int blk = blockIdx.x;              // (b*NH+n)*S + s
  int bn = blk>>10, s = blk&1023, n = bn&3;
  int tid = threadIdx.x;
  __shared__ float sr[D_];
  if(tid<D_) sr[tid] = sx[(size_t)blk*D_ + tid];
  __syncthreads();
  const float* wr;
  if(tid<256){ int e=tid>>6, o=tid&63; wr = wq + ((size_t)((n*NE_+e)*D_+o))*D_; }
  else if(tid<320){ int o=tid-256;     wr = wk + (size_t)(n*D_+o)*D_; }
  else            { int o=tid-320;     wr = wv + (size_t)(n*D_+o)*D_; }
  float acc = 0.f;
  #pragma unroll
  for(int i=0;i<D_;i+=4){
    float4 w = *(const float4*)(wr+i);
    acc += w.x*sr[i] + w.y*sr[i+1] + w.z*sr[i+2] + w.w*sr[i+3];
  }
  if(tid<256){ int e=tid>>6,o=tid&63; q[((size_t)(bn*NE_+e)*S_+s)*D_+o]=acc; }
  else if(tid<320){ int o=tid-256;    kb[((size_t)bn*S_+s)*D_+o]=acc; }
  else            { int o=tid-320;    vb[((size_t)bn*S_+s)*D_+o]=acc; }
}

// ---- K3: flash-style causal attention per (head=(b,n,e), 64-row query tile) ----
__global__ __launch_bounds__(256) void k_attn(const float* __restrict__ q, const float* __restrict__ kb,
        const float* __restrict__ vb, const float* __restrict__ sx, float* __restrict__ attout){
  int blk = blockIdx.x;
  int head = blk>>4, qt = blk&15;
  int bq = head>>2, e = head&3;      // bq = b*NH+n
  int tid = threadIdx.x, r = tid>>4, c = tid&15;
  __shared__ float Qs[64][64];
  __shared__ float Ks[64][64];       // reused as P after scores
  __shared__ float Vs[64][64];
  const float* qp = q  + ((size_t)head*S_ + qt*64)*D_;
  const float* kp = kb + (size_t)bq*S_*D_;
  const float* vp = vb + (size_t)bq*S_*D_;
  // stage Q, pre-scaled by sqrt(D)=8 (bug-faithful multiply)
  #pragma unroll
  for(int it=0; it<4; ++it){
    int g = tid + it*256; int row = g>>4, c0 = (g&15)*4;
    float4 t = *(const float4*)(qp + (size_t)row*D_ + c0);
    t.x*=8.f; t.y*=8.f; t.z*=8.f; t.w*=8.f;
    *(float4*)&Qs[row][swz(row,c0)] = t;
  }
  float O[4][4], m_i[4], l_i[4];
  #pragma unroll
  for(int i=0;i<4;i++){ m_i[i]=-INFINITY; l_i[i]=0.f;
    #pragma unroll
    for(int j=0;j<4;j++) O[i][j]=0.f; }
  const int sw_r = ((r&7)<<2), sw_c = ((c&7)<<2);
  for(int kt=0; kt<=qt; ++kt){
    __syncthreads();                       // prev-iter PV readers done
    #pragma unroll
    for(int it=0; it<4; ++it){             // stage K,V
      int g = tid + it*256; int row = g>>4, c0 = (g&15)*4;
      const size_t goff = (size_t)(kt*64+row)*D_ + c0;
      *(float4*)&Ks[row][swz(row,c0)] = *(const float4*)(kp + goff);
      *(float4*)&Vs[row][swz(row,c0)] = *(const float4*)(vp + goff);
    }
    __syncthreads();
    float sc[4][4];
    #pragma unroll
    for(int i=0;i<4;i++)
      #pragma unroll
      for(int j=0;j<4;j++) sc[i][j]=0.f;
    for(int k4=0;k4<16;k4++){
      int kk = k4*4;
      float qA[4][4], kA[4][4];
      #pragma unroll
      for(int i=0;i<4;i++){
        float4 t = *(const float4*)&Qs[4*r+i][kk ^ sw_r];
        qA[i][0]=t.x; qA[i][1]=t.y; qA[i][2]=t.z; qA[i][3]=t.w;
      }
      #pragma unroll
      for(int j=0;j<4;j++){
        float4 t = *(const float4*)&Ks[4*c+j][kk ^ sw_c];
        kA[j][0]=t.x; kA[j][1]=t.y; kA[j][2]=t.z; kA[j][3]=t.w;
      }
      #pragma unroll
      for(int w=0;w<4;w++)
        #pragma unroll
        for(int i=0;i<4;i++)
          #pragma unroll
          for(int j=0;j<4;j++)
            sc[i][j] += qA[i][w]*kA[j][w];
    }
    __syncthreads();                       // all score reads of Ks done before P overwrite
    if(kt==qt){
      #pragma unroll
      for(int i=0;i<4;i++)
        #pragma unroll
        for(int j=0;j<4;j++)
          if(4*c+j > 4*r+i) sc[i][j] = -INFINITY;
    }
    #pragma unroll
    for(int i=0;i<4;i++){
      float mx = fmaxf(fmaxf(sc[i][0],sc[i][1]),fmaxf(sc[i][2],sc[i][3]));
      #pragma unroll
      for(int off=1; off<16; off<<=1) mx = fmaxf(mx, __shfl_xor(mx,off));
      float mn = fmaxf(m_i[i], mx);
      float scale = __expf(m_i[i]-mn);     // exp(-inf)=0 on first tile
      float rs = 0.f;
      #pragma unroll
      for(int j=0;j<4;j++){ float p=__expf(sc[i][j]-mn); sc[i][j]=p; rs+=p; }
      #pragma unroll
      for(int off=1; off<16; off<<=1) rs += __shfl_xor(rs,off);
      l_i[i] = l_i[i]*scale + rs;
      m_i[i] = mn;
      #pragma unroll
      for(int j=0;j<4;j++) O[i][j]*=scale;
      float4 t; t.x=sc[i][0]; t.y=sc[i][1]; t.z=sc[i][2]; t.w=sc[i][3];
      *(float4*)&Ks[4*r+i][(4*c) ^ sw_r] = t;   // P tile into Ks space
    }
    __syncthreads();
    for(int t4=0;t4<16;t4++){
      float pA[4][4], vA[4][4];
      #pragma unroll
      for(int i=0;i<4;i++){
        float4 t = *(const float4*)&Ks[4*r+i][(4*t4) ^ sw_r];
        pA[i][0]=t.x; pA[i][1]=t.y; pA[i][2]=t.z; pA[i][3]=t.w;
      }
      int sw_t = ((t4&7)<<2);
      #pragma unroll
      for(int tt=0;tt<4;tt++){
        float4 t = *(const float4*)&Vs[4*t4+tt][(4*c) ^ sw_t];
        vA[tt][0]=t.x; vA[tt][1]=t.y; vA[tt][2]=t.z; vA[tt][3]=t.w;
      }
      #pragma unroll
      for(int tt=0;tt<4;tt++)
        #pragma unroll
        for(int i=0;i<4;i++)
          #pragma unroll
          for(int j=0;j<4;j++)
            O[i][j] += pA[i][tt]*vA[tt][j];
    }
  }
  // epilogue: normalize, pad-mask (sx==0, bug-faithful), store as (B,NH,S,NE*D)
  const float* sxp = sx + (size_t)bq*S_*D_;
  float* op = attout + ((size_t)bq*S_ + qt*64)*(NE_*D_) + e*D_;
  #pragma unroll
  for(int i=0;i<4;i++){
    int srow = 4*r+i;
    float inv = 1.f/l_i[i];
    #pragma unroll
    for(int j=0;j<4;j++){
      int dd = 4*c+j;
      float o = O[i][j]*inv;
      if(sxp[(size_t)(qt*64+srow)*D_+dd]==0.f) o=0.f;
      op[(size_t)srow*(NE_*D_) + dd] = o;
    }
  }
}

// ---- K4: expert-gate softmax + mix + batch-indexed residual + LayerNorm ----
__global__ __launch_bounds__(256) void k_mix(const float* __restrict__ attout, const float* __restrict__ gw,
      const float* __restrict__ gb, const float* __restrict__ sx, const float* __restrict__ lng,
      const float* __restrict__ lnb, float* __restrict__ fn){
  int blk = blockIdx.x; int b = blk>>10, s = blk&1023;
  int tid = threadIdx.x, n = tid>>6, d = tid&63;
  const float* row = attout + ((size_t)(b*NH_+n)*S_ + s)*(NE_*D_);
  float o[NE_];
  #pragma unroll
  for(int e2=0;e2<NE_;e2++) o[e2] = row[e2*D_+d];
  float lg[NE_];
  #pragma unroll
  for(int e=0;e<NE_;e++){
    const float* g = gw + (size_t)(n*NE_+e)*(NE_*D_);
    float p = 0.f;
    #pragma unroll
    for(int e2=0;e2<NE_;e2++) p += o[e2]*g[e2*D_+d];
    #pragma unroll
    for(int off=1; off<64; off<<=1) p += __shfl_xor(p,off);
    lg[e] = p + gb[n*NE_+e];
  }
  float mx = fmaxf(fmaxf(lg[0],lg[1]),fmaxf(lg[2],lg[3]));
  float se = 0.f;
  #pragma unroll
  for(int e=0;e<NE_;e++){ lg[e]=__expf(lg[e]-mx); se+=lg[e]; }
  float inv = 1.f/se;
  float mixed = 0.f;
  #pragma unroll
  for(int e=0;e<NE_;e++) mixed += o[e]*lg[e]*inv;
  // bug-faithful residual: sx[batch=n, head=n, s, d]
  float resid = sx[((size_t)(n*NH_+n)*S_ + s)*D_ + d];
  float t = mixed + resid;
  float mean = t;
  #pragma unroll
  for(int off=1; off<64; off<<=1) mean += __shfl_xor(mean,off);
  mean *= (1.f/64.f);
  float xc = t - mean;
  float var = xc*xc;
  #pragma unroll
  for(int off=1; off<64; off<<=1) var += __shfl_xor(var,off);
  var *= (1.f/64.f);
  float y = xc*rsqrtf(var+EPS_)*lng[d] + lnb[d];
  fn[(size_t)blk*H_ + tid] = y;   // tid = n*64+d  -> f_n[b,s,h]
}

// ---- K5: per-head FFN + LayerNorm + final head-gate softmax ----
__global__ __launch_bounds__(256) void k_ffn(const float* __restrict__ fn, const float* __restrict__ w1,
      const float* __restrict__ b1, const float* __restrict__ w2, const float* __restrict__ b2,
      const float* __restrict__ fg, const float* __restrict__ fb, const float* __restrict__ fgw,
      float* __restrict__ out){
  int blk = blockIdx.x;
  int tid = threadIdx.x, n = tid>>6, d = tid&63;
  __shared__ float fxs[H_];
  __shared__ float h1s[H_];
  __shared__ float fos[H_];
  __shared__ float red[NH_][NH_];
  fxs[tid] = fn[(size_t)blk*H_ + tid];
  __syncthreads();
  const float* fxh = &fxs[n*D_];
  float fxd = fxh[d];
  float acc = b1[d];
  const float* w1r = w1 + (size_t)d*D_;
  #pragma unroll
  for(int i=0;i<D_;i+=4){
    float4 w = *(const float4*)(w1r+i);
    acc += w.x*fxh[i] + w.y*fxh[i+1] + w.z*fxh[i+2] + w.w*fxh[i+3];
  }
  float h1 = (fxd==0.f)?0.f:acc;     // bug-faithful element mask
  h1 = fmaxf(h1,0.f);
  h1s[tid] = h1;
  __syncthreads();
  const float* h1h = &h1s[n*D_];
  float acc2 = b2[d];
  const float* w2r = w2 + (size_t)d*D_;
  #pragma unroll
  for(int i=0;i<D_;i+=4){
    float4 w = *(const float4*)(w2r+i);
    acc2 += w.x*h1h[i] + w.y*h1h[i+1] + w.z*h1h[i+2] + w.w*h1h[i+3];
  }
  float h2 = (fxd==0.f)?0.f:acc2;
  float t = h2 + fxd;
  float mean = t;
  #pragma unroll
  for(int off=1; off<64; off<<=1) mean += __shfl_xor(mean,off);
  mean *= (1.f/64.f);
  float xc = t-mean;
  float var = xc*xc;
  #pragma unroll
  for(int off=1; off<64; off<<=1) var += __shfl_xor(var,off);
  var *= (1.f/64.f);
  float y = xc*rsqrtf(var+EPS_)*fg[d] + fb[d];
  fos[tid] = y;
  __syncthreads();
  float p[NH_];
  #pragma unroll
  for(int j=0;j<NH_;j++){
    float pv = fos[tid]*fgw[(size_t)j*H_ + tid];
    #pragma unroll
    for(int off=1; off<64; off<<=1) pv += __shfl_xor(pv,off);
    p[j]=pv;
  }
  if(d==0){
    #pragma unroll
    for(int j=0;j<NH_;j++) red[n][j]=p[j];
  }
  __syncthreads();
  float lg[NH_];
  #pragma unroll
  for(int j=0;j<NH_;j++) lg[j] = red[0][j]+red[1][j]+red[2][j]+red[3][j];
  float mx2 = fmaxf(fmaxf(lg[0],lg[1]),fmaxf(lg[2],lg[3]));
  float se=0.f;
  #pragma unroll
  for(int j=0;j<NH_;j++){ lg[j]=__expf(lg[j]-mx2); se+=lg[j]; }
  float gsn = lg[n]/se;
  out[(size_t)blk*H_ + tid] = y*gsn;
}

extern "C" void kernel_launch(void* const* d_in, const int* in_sizes, int n_in,
                              void* d_out, int out_size, void* d_ws, size_t ws_size,
                              hipStream_t stream){
  const float* x      = (const float*)d_in[0];
  const float* hl_w   = (const float*)d_in[1];
  const float* hl_b   = (const float*)d_in[2];
  const float* wq     = (const float*)d_in[3];
  const float* wk     = (const float*)d_in[4];
  const float* wv     = (const float*)d_in[5];
  const float* gate_w = (const float*)d_in[6];
  const float* gate_b = (const float*)d_in[7];
  const float* ln_g   = (const float*)d_in[8];
  const float* ln_b   = (const float*)d_in[9];
  const float* fc1_w  = (const float*)d_in[10];
  const float* fc1_b  = (const float*)d_in[11];
  const float* fc2_w  = (const float*)d_in[12];
  const float* fc2_b  = (const float*)d_in[13];
  const float* fnorm_g= (const float*)d_in[14];
  const float* fnorm_b= (const float*)d_in[15];
  const float* fgate_w= (const float*)d_in[16];

  float* ws = (float*)d_ws;
  float* sx     = ws;                                   // 4*4*1024*64        = 1M f32
  float* q      = sx + (size_t)B_*NH_*S_*D_;            // 4*4*4*1024*64      = 4M f32
  float* kbuf   = q + (size_t)B_*NH_*NE_*S_*D_;         // 1M f32
  float* vbuf   = kbuf + (size_t)B_*NH_*S_*D_;          // 1M f32
  float* attout = vbuf + (size_t)B_*NH_*S_*D_;          // 4M f32
  float* f_n    = attout + (size_t)B_*NH_*S_*NE_*D_;    // 1M f32

  k_sx  <<<B_*S_,        256, 0, stream>>>(x, hl_w, hl_b, sx);
  k_qkv <<<B_*NH_*S_,    384, 0, stream>>>(sx, wq, wk, wv, q, kbuf, vbuf);
  k_attn<<<B_*NH_*NE_*(S_/64), 256, 0, stream>>>(q, kbuf, vbuf, sx, attout);
  k_mix <<<B_*S_,        256, 0, stream>>>(attout, gate_w, gate_b, sx, ln_g, ln_b, f_n);
  k_ffn <<<B_*S_,        256, 0, stream>>>(f_n, fc1_w, fc1_b, fc2_w, fc2_b,
                                           fnorm_g, fnorm_b, fgate_w, (float*)d_out);
}

// Round 3
// 133.770 us; speedup vs baseline: 4.9792x; 4.9792x over previous
//
#include <hip/hip_runtime.h>
#include <math.h>

typedef unsigned short u16;
typedef __attribute__((ext_vector_type(8))) unsigned short us8;
typedef __attribute__((ext_vector_type(8))) short bf16x8;   // MFMA A/B frag (8 bf16, 4 VGPR)
typedef __attribute__((ext_vector_type(4))) float f32x4;    // MFMA C/D frag

constexpr int B_ = 4, S_ = 1024, H_ = 256, NH_ = 4, NE_ = 4, D_ = 64;
constexpr float EPS_ = 1e-8f;

__device__ __forceinline__ u16 f2bf(float f){
  unsigned u = __float_as_uint(f);
  unsigned rnd = 0x7fffu + ((u>>16)&1u);
  return (u16)((u + rnd)>>16);
}
__device__ __forceinline__ us8 pack8(float4 a, float4 b){
  us8 r;
  r[0]=f2bf(a.x); r[1]=f2bf(a.y); r[2]=f2bf(a.z); r[3]=f2bf(a.w);
  r[4]=f2bf(b.x); r[5]=f2bf(b.y); r[6]=f2bf(b.z); r[7]=f2bf(b.w);
  return r;
}
#define MFMA16(a,b,c) __builtin_amdgcn_mfma_f32_16x16x32_bf16((bf16x8)(a),(bf16x8)(b),(c),0,0,0)

// ---- K1: sx = x . hl_w^T + hl_b  (MFMA GEMM M=4096 N=256 K=256; BM=64 BN=32 BK=64)
__global__ __launch_bounds__(256) void k_sx(const float* __restrict__ x, const float* __restrict__ hlw,
                                            const float* __restrict__ hlb,
                                            float* __restrict__ sx, u16* __restrict__ sxb){
  int mt = blockIdx.x >> 3, nt = blockIdx.x & 7;
  int tid = threadIdx.x, w = tid>>6, l = tid&63, lr = l>>4, lc = l&15;
  __shared__ u16 Xs[64*64];
  __shared__ u16 Ws[32*64];
  const int swl = (lc&7)<<3;
  f32x4 acc[2] = {{0,0,0,0},{0,0,0,0}};
  for(int ks=0; ks<4; ++ks){
    __syncthreads();
    // stage X tile (f32 -> bf16, XOR-swizzled)
    #pragma unroll
    for(int it=0; it<2; ++it){
      int c0 = w*8 + it*32;
      const float* xp = x + ((size_t)(mt*64+l))*H_ + ks*64 + c0;
      float4 a = *(const float4*)xp, b = *(const float4*)(xp+4);
      *(us8*)&Xs[l*64 + (c0 ^ ((l&7)<<3))] = pack8(a,b);
    }
    { // stage W tile: rows nt*32+(tid&31), cols (tid>>5)*8
      int row = tid&31, c0 = (tid>>5)*8;
      const float* wp = hlw + ((size_t)(nt*32+row))*H_ + ks*64 + c0;
      float4 a = *(const float4*)wp, b = *(const float4*)(wp+4);
      *(us8*)&Ws[row*64 + (c0 ^ ((row&7)<<3))] = pack8(a,b);
    }
    __syncthreads();
    bf16x8 a0 = *(const bf16x8*)&Xs[(w*16+lc)*64 + ((lr*8   ) ^ swl)];
    bf16x8 a1 = *(const bf16x8*)&Xs[(w*16+lc)*64 + ((lr*8+32) ^ swl)];
    #pragma unroll
    for(int j=0;j<2;j++){
      const u16* wr = &Ws[(j*16+lc)*64];
      bf16x8 b0 = *(const bf16x8*)(wr + ((lr*8   ) ^ swl));
      bf16x8 b1 = *(const bf16x8*)(wr + ((lr*8+32) ^ swl));
      acc[j] = MFMA16(a0,b0,acc[j]);
      acc[j] = MFMA16(a1,b1,acc[j]);
    }
  }
  #pragma unroll
  for(int j=0;j<2;j++){
    int col = nt*32 + j*16 + lc;          // = n*64+d
    int n = col>>6, d = col&63;
    float bias = hlb[col];
    #pragma unroll
    for(int r=0;r<4;r++){
      int m = mt*64 + w*16 + lr*4 + r;
      int b = m>>10, s = m&1023;
      float v = acc[j][r] + bias;
      size_t idx = ((size_t)(b*NH_+n)*S_ + s)*D_ + d;
      sx[idx] = v; sxb[idx] = f2bf(v);
    }
  }
}

// ---- K2: q/k/v projections per head (MFMA; N=384 split in halves of 192)
__global__ __launch_bounds__(256) void k_qkv(const u16* __restrict__ sxb, const float* __restrict__ wq,
            const float* __restrict__ wk, const float* __restrict__ wv,
            u16* __restrict__ qb, u16* __restrict__ kbf, u16* __restrict__ vbf){
  int bid = blockIdx.x;
  int half = bid&1, mt = (bid>>1)&63, n = bid>>7;
  int tid = threadIdx.x, w = tid>>6, l = tid&63, lr = l>>4, lc = l&15;
  __shared__ u16 As[64*64];
  __shared__ u16 Ws[192*64];
  const int swl = (lc&7)<<3;
  int b = (mt*64)>>10, s0 = (mt*64)&1023;
  // stage A (already bf16)
  #pragma unroll
  for(int it=0; it<2; ++it){
    int c0 = w*8 + it*32;
    us8 v = *(const us8*)(sxb + ((size_t)(b*NH_+n)*S_ + s0 + l)*D_ + c0);
    *(us8*)&As[l*64 + (c0 ^ ((l&7)<<3))] = v;
  }
  // stage W (f32 -> bf16): 3 chunks of 64 rows
  #pragma unroll
  for(int ch=0; ch<3; ++ch){
    int o = half*192 + ch*64 + l;
    const float* src;
    if(o < 256)      src = wq + ((size_t)((n*NE_ + (o>>6))*D_ + (o&63)))*D_;
    else if(o < 320) src = wk + ((size_t)(n*D_ + (o-256)))*D_;
    else             src = wv + ((size_t)(n*D_ + (o-320)))*D_;
    #pragma unroll
    for(int it=0; it<2; ++it){
      int c0 = w*8 + it*32;
      float4 a = *(const float4*)(src+c0), bb = *(const float4*)(src+c0+4);
      *(us8*)&Ws[(ch*64+l)*64 + (c0 ^ ((l&7)<<3))] = pack8(a,bb);
    }
  }
  __syncthreads();
  bf16x8 a0 = *(const bf16x8*)&As[(w*16+lc)*64 + ((lr*8   ) ^ swl)];
  bf16x8 a1 = *(const bf16x8*)&As[(w*16+lc)*64 + ((lr*8+32) ^ swl)];
  f32x4 acc[12];
  #pragma unroll
  for(int j=0;j<12;j++) acc[j] = (f32x4){0,0,0,0};
  #pragma unroll
  for(int j=0;j<12;j++){
    const u16* wr = &Ws[(j*16+lc)*64];
    bf16x8 b0 = *(const bf16x8*)(wr + ((lr*8   ) ^ swl));
    bf16x8 b1 = *(const bf16x8*)(wr + ((lr*8+32) ^ swl));
    acc[j] = MFMA16(a0,b0,acc[j]);
    acc[j] = MFMA16(a1,b1,acc[j]);
  }
  #pragma unroll
  for(int j=0;j<12;j++){
    int o = half*192 + j*16 + lc;
    #pragma unroll
    for(int r=0;r<4;r++){
      int s = s0 + w*16 + lr*4 + r;
      float v = acc[j][r];
      if(o < 256){       // q, bug-faithful *sqrt(D)=8 folded in
        int e = o>>6, d = o&63;
        qb[((size_t)((b*NH_+n)*NE_+e)*S_ + s)*D_ + d] = f2bf(v*8.f);
      } else if(o < 320){
        kbf[((size_t)(b*NH_+n)*S_ + s)*D_ + (o-256)] = f2bf(v);
      } else {
        vbf[((size_t)(b*NH_+n)*S_ + s)*D_ + (o-320)] = f2bf(v);
      }
    }
  }
}

// ---- K3: MFMA flash attention; block = (head, pair p) -> q-tiles {p, 15-p} (balanced 17 steps)
__global__ __launch_bounds__(256) void k_attn(const u16* __restrict__ qb, const u16* __restrict__ kb,
        const u16* __restrict__ vb, const float* __restrict__ sx, float* __restrict__ attout){
  int bid = blockIdx.x;
  int head = bid>>3, p = bid&7;
  int bq = head>>2, e = head&3;
  int tid = threadIdx.x, w = tid>>6, l = tid&63, lr = l>>4, lc = l&15;
  __shared__ u16 Ks[2][64*64];
  __shared__ u16 VT[2][64*64];
  __shared__ u16 Pb[4][16*64];
  const u16* kh = kb + (size_t)bq*S_*D_;
  const u16* vh = vb + (size_t)bq*S_*D_;
  const int swl = (lc&7)<<3;
  const int swst = (l&7)<<3;           // staging swizzle (row = l)

  #pragma unroll
  for(int ph=0; ph<2; ++ph){
    int qt = ph ? (15-p) : p;
    // Q fragments straight from global (bf16, pre-scaled by 8)
    const u16* qrow = qb + ((size_t)head*S_ + qt*64 + w*16 + lc)*D_;
    bf16x8 qf0 = *(const bf16x8*)(qrow + lr*8);
    bf16x8 qf1 = *(const bf16x8*)(qrow + lr*8 + 32);
    f32x4 Oa[4]; float m_i[4], l_i[4];
    #pragma unroll
    for(int j=0;j<4;j++) Oa[j] = (f32x4){0,0,0,0};
    #pragma unroll
    for(int r=0;r<4;r++){ m_i[r] = -INFINITY; l_i[r] = 0.f; }

    us8 rg[4];
    __syncthreads();                       // protect buffers from previous phase readers
    { // prologue: stage kt=0 into buf 0
      const u16* kr = kh + (size_t)(qt*0 + 0)*64*D_ + (size_t)l*D_;   // kt=0
      const u16* vr = vh + (size_t)l*D_;
      int c0 = w*8;
      rg[0] = *(const us8*)(kr + c0);      rg[1] = *(const us8*)(kr + c0 + 32);
      rg[2] = *(const us8*)(vr + c0);      rg[3] = *(const us8*)(vr + c0 + 32);
      *(us8*)&Ks[0][l*64 + ( c0      ^ swst)] = rg[0];
      *(us8*)&Ks[0][l*64 + ((c0+32)  ^ swst)] = rg[1];
      #pragma unroll
      for(int i=0;i<8;i++){ int d=c0+i;    VT[0][d*64 + (l ^ ((d&7)<<3))] = rg[2][i]; }
      #pragma unroll
      for(int i=0;i<8;i++){ int d=c0+32+i; VT[0][d*64 + (l ^ ((d&7)<<3))] = rg[3][i]; }
    }
    for(int kt=0; kt<=qt; ++kt){
      int cur = kt&1;
      __syncthreads();
      bool more = kt < qt;
      if(more){                            // T14: issue next-tile loads before compute
        const u16* kr = kh + ((size_t)(kt+1)*64 + l)*D_;
        const u16* vr = vh + ((size_t)(kt+1)*64 + l)*D_;
        int c0 = w*8;
        rg[0] = *(const us8*)(kr + c0);    rg[1] = *(const us8*)(kr + c0 + 32);
        rg[2] = *(const us8*)(vr + c0);    rg[3] = *(const us8*)(vr + c0 + 32);
      }
      // S = Q K^T  (16x64 per wave)
      f32x4 Sa[4];
      #pragma unroll
      for(int j=0;j<4;j++){
        const u16* kr = &Ks[cur][(j*16+lc)*64];
        bf16x8 b0 = *(const bf16x8*)(kr + ((lr*8   ) ^ swl));
        bf16x8 b1 = *(const bf16x8*)(kr + ((lr*8+32) ^ swl));
        f32x4 z = (f32x4){0,0,0,0};
        z = MFMA16(qf0,b0,z);
        z = MFMA16(qf1,b1,z);
        Sa[j] = z;
      }
      // online softmax (rows = lr*4+r, cols = j*16+lc)
      #pragma unroll
      for(int r=0;r<4;r++){
        int qr = w*16 + lr*4 + r;
        float sv[4];
        #pragma unroll
        for(int j=0;j<4;j++){
          sv[j] = Sa[j][r];
          if(kt==qt && (j*16+lc) > qr) sv[j] = -INFINITY;
        }
        float mx = fmaxf(fmaxf(sv[0],sv[1]),fmaxf(sv[2],sv[3]));
        #pragma unroll
        for(int off=1; off<16; off<<=1) mx = fmaxf(mx, __shfl_xor(mx,off));
        float mn = fmaxf(m_i[r], mx);
        float sc = __expf(m_i[r]-mn);
        float rs = 0.f;
        #pragma unroll
        for(int j=0;j<4;j++){ sv[j] = __expf(sv[j]-mn); rs += sv[j]; }
        #pragma unroll
        for(int off=1; off<16; off<<=1) rs += __shfl_xor(rs,off);
        l_i[r] = l_i[r]*sc + rs;
        m_i[r] = mn;
        #pragma unroll
        for(int j=0;j<4;j++) Oa[j][r] *= sc;
        int prow = lr*4+r, psw = (prow&7)<<3;
        #pragma unroll
        for(int j=0;j<4;j++) Pb[w][prow*64 + ((j*16+lc) ^ psw)] = f2bf(sv[j]);
      }
      // PV (P row = lc, contiguous swizzled A-frag; LDS ops of a wave are in-order)
      asm volatile("s_waitcnt lgkmcnt(0)" ::: "memory");
      bf16x8 pA0 = *(const bf16x8*)&Pb[w][lc*64 + ((lr*8   ) ^ swl)];
      bf16x8 pA1 = *(const bf16x8*)&Pb[w][lc*64 + ((lr*8+32) ^ swl)];
      #pragma unroll
      for(int jd=0;jd<4;jd++){
        const u16* vr = &VT[cur][(jd*16+lc)*64];
        bf16x8 v0 = *(const bf16x8*)(vr + ((lr*8   ) ^ swl));
        bf16x8 v1 = *(const bf16x8*)(vr + ((lr*8+32) ^ swl));
        Oa[jd] = MFMA16(pA0,v0,Oa[jd]);
        Oa[jd] = MFMA16(pA1,v1,Oa[jd]);
      }
      if(more){                            // write next tile into other buffer
        int nb = cur^1, c0 = w*8;
        *(us8*)&Ks[nb][l*64 + ( c0     ^ swst)] = rg[0];
        *(us8*)&Ks[nb][l*64 + ((c0+32) ^ swst)] = rg[1];
        #pragma unroll
        for(int i=0;i<8;i++){ int d=c0+i;    VT[nb][d*64 + (l ^ ((d&7)<<3))] = rg[2][i]; }
        #pragma unroll
        for(int i=0;i<8;i++){ int d=c0+32+i; VT[nb][d*64 + (l ^ ((d&7)<<3))] = rg[3][i]; }
      }
    }
    // epilogue: normalize, bug-faithful sx==0 mask, store (B,NH,S,NE*D)
    #pragma unroll
    for(int r=0;r<4;r++){
      int qg = qt*64 + w*16 + lr*4 + r;
      float inv = 1.f/l_i[r];
      #pragma unroll
      for(int jd=0;jd<4;jd++){
        int d = jd*16 + lc;
        float o = Oa[jd][r]*inv;
        if(sx[((size_t)bq*S_ + qg)*D_ + d] == 0.f) o = 0.f;
        attout[((size_t)bq*S_ + qg)*(NE_*D_) + e*D_ + d] = o;
      }
    }
  }
}

// ---- K4: expert-gate softmax + mix + batch-indexed residual + LayerNorm ----
__global__ __launch_bounds__(256) void k_mix(const float* __restrict__ attout, const float* __restrict__ gw,
      const float* __restrict__ gb, const float* __restrict__ sx, const float* __restrict__ lng,
      const float* __restrict__ lnb, float* __restrict__ fn){
  int blk = blockIdx.x; int b = blk>>10, s = blk&1023;
  int tid = threadIdx.x, n = tid>>6, d = tid&63;
  const float* row = attout + ((size_t)(b*NH_+n)*S_ + s)*(NE_*D_);
  float o[NE_];
  #pragma unroll
  for(int e2=0;e2<NE_;e2++) o[e2] = row[e2*D_+d];
  float lg[NE_];
  #pragma unroll
  for(int e=0;e<NE_;e++){
    const float* g = gw + (size_t)(n*NE_+e)*(NE_*D_);
    float p = 0.f;
    #pragma unroll
    for(int e2=0;e2<NE_;e2++) p += o[e2]*g[e2*D_+d];
    #pragma unroll
    for(int off=1; off<64; off<<=1) p += __shfl_xor(p,off);
    lg[e] = p + gb[n*NE_+e];
  }
  float mx = fmaxf(fmaxf(lg[0],lg[1]),fmaxf(lg[2],lg[3]));
  float se = 0.f;
  #pragma unroll
  for(int e=0;e<NE_;e++){ lg[e]=__expf(lg[e]-mx); se+=lg[e]; }
  float inv = 1.f/se;
  float mixed = 0.f;
  #pragma unroll
  for(int e=0;e<NE_;e++) mixed += o[e]*lg[e]*inv;
  float resid = sx[((size_t)(n*NH_+n)*S_ + s)*D_ + d];  // bug-faithful batch-indexed residual
  float t = mixed + resid;
  float mean = t;
  #pragma unroll
  for(int off=1; off<64; off<<=1) mean += __shfl_xor(mean,off);
  mean *= (1.f/64.f);
  float xc = t - mean;
  float var = xc*xc;
  #pragma unroll
  for(int off=1; off<64; off<<=1) var += __shfl_xor(var,off);
  var *= (1.f/64.f);
  float y = xc*rsqrtf(var+EPS_)*lng[d] + lnb[d];
  fn[(size_t)blk*H_ + tid] = y;
}

// ---- K5: per-head FFN + LayerNorm + final head-gate softmax ----
__global__ __launch_bounds__(256) void k_ffn(const float* __restrict__ fn, const float* __restrict__ w1,
      const float* __restrict__ b1, const float* __restrict__ w2, const float* __restrict__ b2,
      const float* __restrict__ fg, const float* __restrict__ fb, const float* __restrict__ fgw,
      float* __restrict__ out){
  int blk = blockIdx.x;
  int tid = threadIdx.x, n = tid>>6, d = tid&63;
  __shared__ float fxs[H_];
  __shared__ float h1s[H_];
  __shared__ float fos[H_];
  __shared__ float red[NH_][NH_];
  fxs[tid] = fn[(size_t)blk*H_ + tid];
  __syncthreads();
  const float* fxh = &fxs[n*D_];
  float fxd = fxh[d];
  float acc = b1[d];
  const float* w1r = w1 + (size_t)d*D_;
  #pragma unroll
  for(int i=0;i<D_;i+=4){
    float4 w = *(const float4*)(w1r+i);
    acc += w.x*fxh[i] + w.y*fxh[i+1] + w.z*fxh[i+2] + w.w*fxh[i+3];
  }
  float h1 = (fxd==0.f)?0.f:acc;
  h1 = fmaxf(h1,0.f);
  h1s[tid] = h1;
  __syncthreads();
  const float* h1h = &h1s[n*D_];
  float acc2 = b2[d];
  const float* w2r = w2 + (size_t)d*D_;
  #pragma unroll
  for(int i=0;i<D_;i+=4){
    float4 w = *(const float4*)(w2r+i);
    acc2 += w.x*h1h[i] + w.y*h1h[i+1] + w.z*h1h[i+2] + w.w*h1h[i+3];
  }
  float h2 = (fxd==0.f)?0.f:acc2;
  float t = h2 + fxd;
  float mean = t;
  #pragma unroll
  for(int off=1; off<64; off<<=1) mean += __shfl_xor(mean,off);
  mean *= (1.f/64.f);
  float xc = t-mean;
  float var = xc*xc;
  #pragma unroll
  for(int off=1; off<64; off<<=1) var += __shfl_xor(var,off);
  var *= (1.f/64.f);
  float y = xc*rsqrtf(var+EPS_)*fg[d] + fb[d];
  fos[tid] = y;
  __syncthreads();
  float pr[NH_];
  #pragma unroll
  for(int j=0;j<NH_;j++){
    float pv = fos[tid]*fgw[(size_t)j*H_ + tid];
    #pragma unroll
    for(int off=1; off<64; off<<=1) pv += __shfl_xor(pv,off);
    pr[j]=pv;
  }
  if(d==0){
    #pragma unroll
    for(int j=0;j<NH_;j++) red[n][j]=pr[j];
  }
  __syncthreads();
  float lg[NH_];
  #pragma unroll
  for(int j=0;j<NH_;j++) lg[j] = red[0][j]+red[1][j]+red[2][j]+red[3][j];
  float mx2 = fmaxf(fmaxf(lg[0],lg[1]),fmaxf(lg[2],lg[3]));
  float se=0.f;
  #pragma unroll
  for(int j=0;j<NH_;j++){ lg[j]=__expf(lg[j]-mx2); se+=lg[j]; }
  float gsn = lg[n]/se;
  out[(size_t)blk*H_ + tid] = y*gsn;
}

extern "C" void kernel_launch(void* const* d_in, const int* in_sizes, int n_in,
                              void* d_out, int out_size, void* d_ws, size_t ws_size,
                              hipStream_t stream){
  const float* x      = (const float*)d_in[0];
  const float* hl_w   = (const float*)d_in[1];
  const float* hl_b   = (const float*)d_in[2];
  const float* wq     = (const float*)d_in[3];
  const float* wk     = (const float*)d_in[4];
  const float* wv     = (const float*)d_in[5];
  const float* gate_w = (const float*)d_in[6];
  const float* gate_b = (const float*)d_in[7];
  const float* ln_g   = (const float*)d_in[8];
  const float* ln_b   = (const float*)d_in[9];
  const float* fc1_w  = (const float*)d_in[10];
  const float* fc1_b  = (const float*)d_in[11];
  const float* fc2_w  = (const float*)d_in[12];
  const float* fc2_b  = (const float*)d_in[13];
  const float* fnorm_g= (const float*)d_in[14];
  const float* fnorm_b= (const float*)d_in[15];
  const float* fgate_w= (const float*)d_in[16];

  const size_t NSD = (size_t)B_*NH_*S_*D_;       // 1M
  float* ws     = (float*)d_ws;
  float* sx     = ws;                            // 1M f32
  float* attout = sx + NSD;                      // 4M f32
  float* f_n    = attout + NSD*NE_;              // 1M f32
  u16*   sxb    = (u16*)(f_n + NSD);             // 1M u16
  u16*   qb     = sxb + NSD;                     // 4M u16
  u16*   kbf    = qb + NSD*NE_;                  // 1M u16
  u16*   vbf    = kbf + NSD;                     // 1M u16

  k_sx  <<<512,  256, 0, stream>>>(x, hl_w, hl_b, sx, sxb);
  k_qkv <<<512,  256, 0, stream>>>(sxb, wq, wk, wv, qb, kbf, vbf);
  k_attn<<<512,  256, 0, stream>>>(qb, kbf, vbf, sx, attout);
  k_mix <<<B_*S_,256, 0, stream>>>(attout, gate_w, gate_b, sx, ln_g, ln_b, f_n);
  k_ffn <<<B_*S_,256, 0, stream>>>(f_n, fc1_w, fc1_b, fc2_w, fc2_b,
                                   fnorm_g, fnorm_b, fgate_w, (float*)d_out);
}

// Round 4
// 73.991 us; speedup vs baseline: 9.0020x; 1.8079x over previous
//
#include <hip/hip_runtime.h>
#include <math.h>

typedef unsigned short u16;
typedef __attribute__((ext_vector_type(8))) unsigned short us8;
typedef __attribute__((ext_vector_type(4))) unsigned short us4;
typedef __attribute__((ext_vector_type(8))) short bf16x8;   // MFMA A/B frag (8 bf16, 4 VGPR)
typedef __attribute__((ext_vector_type(4))) float f32x4;    // MFMA C/D frag

constexpr int B_ = 4, S_ = 1024, H_ = 256, NH_ = 4, NE_ = 4, D_ = 64;
constexpr float EPS_ = 1e-8f;

__device__ __forceinline__ u16 f2bf(float f){
  unsigned u = __float_as_uint(f);
  unsigned rnd = 0x7fffu + ((u>>16)&1u);
  return (u16)((u + rnd)>>16);
}
__device__ __forceinline__ us8 pack8(float4 a, float4 b){
  us8 r;
  r[0]=f2bf(a.x); r[1]=f2bf(a.y); r[2]=f2bf(a.z); r[3]=f2bf(a.w);
  r[4]=f2bf(b.x); r[5]=f2bf(b.y); r[6]=f2bf(b.z); r[7]=f2bf(b.w);
  return r;
}
#define MFMA16(a,b,c) __builtin_amdgcn_mfma_f32_16x16x32_bf16((bf16x8)(a),(bf16x8)(b),(c),0,0,0)

// ---- K1: sx = x . hl_w^T + hl_b  (MFMA GEMM M=4096 N=256 K=256; BM=64 BN=32 BK=64)
__global__ __launch_bounds__(256) void k_sx(const float* __restrict__ x, const float* __restrict__ hlw,
                                            const float* __restrict__ hlb,
                                            float* __restrict__ sx, u16* __restrict__ sxb){
  int mt = blockIdx.x >> 3, nt = blockIdx.x & 7;
  int tid = threadIdx.x, w = tid>>6, l = tid&63, lr = l>>4, lc = l&15;
  __shared__ u16 Xs[64*64];
  __shared__ u16 Ws[32*64];
  const int swl = (lc&7)<<3;
  f32x4 acc[2] = {{0,0,0,0},{0,0,0,0}};
  for(int ks=0; ks<4; ++ks){
    __syncthreads();
    #pragma unroll
    for(int it=0; it<2; ++it){
      int c0 = w*8 + it*32;
      const float* xp = x + ((size_t)(mt*64+l))*H_ + ks*64 + c0;
      float4 a = *(const float4*)xp, b = *(const float4*)(xp+4);
      *(us8*)&Xs[l*64 + (c0 ^ ((l&7)<<3))] = pack8(a,b);
    }
    { int row = tid&31, c0 = (tid>>5)*8;
      const float* wp = hlw + ((size_t)(nt*32+row))*H_ + ks*64 + c0;
      float4 a = *(const float4*)wp, b = *(const float4*)(wp+4);
      *(us8*)&Ws[row*64 + (c0 ^ ((row&7)<<3))] = pack8(a,b);
    }
    __syncthreads();
    bf16x8 a0 = *(const bf16x8*)&Xs[(w*16+lc)*64 + ((lr*8   ) ^ swl)];
    bf16x8 a1 = *(const bf16x8*)&Xs[(w*16+lc)*64 + ((lr*8+32) ^ swl)];
    #pragma unroll
    for(int j=0;j<2;j++){
      const u16* wr = &Ws[(j*16+lc)*64];
      bf16x8 b0 = *(const bf16x8*)(wr + ((lr*8   ) ^ swl));
      bf16x8 b1 = *(const bf16x8*)(wr + ((lr*8+32) ^ swl));
      acc[j] = MFMA16(a0,b0,acc[j]);
      acc[j] = MFMA16(a1,b1,acc[j]);
    }
  }
  #pragma unroll
  for(int j=0;j<2;j++){
    int col = nt*32 + j*16 + lc;
    int n = col>>6, d = col&63;
    float bias = hlb[col];
    #pragma unroll
    for(int r=0;r<4;r++){
      int m = mt*64 + w*16 + lr*4 + r;
      int b = m>>10, s = m&1023;
      float v = acc[j][r] + bias;
      size_t idx = ((size_t)(b*NH_+n)*S_ + s)*D_ + d;
      sx[idx] = v; sxb[idx] = f2bf(v);
    }
  }
}

// ---- K2: q/k/v projections per head (MFMA; N=384 split in halves of 192)
__global__ __launch_bounds__(256) void k_qkv(const u16* __restrict__ sxb, const float* __restrict__ wq,
            const float* __restrict__ wk, const float* __restrict__ wv,
            u16* __restrict__ qb, u16* __restrict__ kbf, u16* __restrict__ vbf){
  int bid = blockIdx.x;
  int half = bid&1, mt = (bid>>1)&63, n = bid>>7;
  int tid = threadIdx.x, w = tid>>6, l = tid&63, lr = l>>4, lc = l&15;
  __shared__ u16 As[64*64];
  __shared__ u16 Ws[192*64];
  const int swl = (lc&7)<<3;
  int b = (mt*64)>>10, s0 = (mt*64)&1023;
  #pragma unroll
  for(int it=0; it<2; ++it){
    int c0 = w*8 + it*32;
    us8 v = *(const us8*)(sxb + ((size_t)(b*NH_+n)*S_ + s0 + l)*D_ + c0);
    *(us8*)&As[l*64 + (c0 ^ ((l&7)<<3))] = v;
  }
  #pragma unroll
  for(int ch=0; ch<3; ++ch){
    int o = half*192 + ch*64 + l;
    const float* src;
    if(o < 256)      src = wq + ((size_t)((n*NE_ + (o>>6))*D_ + (o&63)))*D_;
    else if(o < 320) src = wk + ((size_t)(n*D_ + (o-256)))*D_;
    else             src = wv + ((size_t)(n*D_ + (o-320)))*D_;
    #pragma unroll
    for(int it=0; it<2; ++it){
      int c0 = w*8 + it*32;
      float4 a = *(const float4*)(src+c0), bb = *(const float4*)(src+c0+4);
      *(us8*)&Ws[(ch*64+l)*64 + (c0 ^ ((l&7)<<3))] = pack8(a,bb);
    }
  }
  __syncthreads();
  bf16x8 a0 = *(const bf16x8*)&As[(w*16+lc)*64 + ((lr*8   ) ^ swl)];
  bf16x8 a1 = *(const bf16x8*)&As[(w*16+lc)*64 + ((lr*8+32) ^ swl)];
  f32x4 acc[12];
  #pragma unroll
  for(int j=0;j<12;j++) acc[j] = (f32x4){0,0,0,0};
  #pragma unroll
  for(int j=0;j<12;j++){
    const u16* wr = &Ws[(j*16+lc)*64];
    bf16x8 b0 = *(const bf16x8*)(wr + ((lr*8   ) ^ swl));
    bf16x8 b1 = *(const bf16x8*)(wr + ((lr*8+32) ^ swl));
    acc[j] = MFMA16(a0,b0,acc[j]);
    acc[j] = MFMA16(a1,b1,acc[j]);
  }
  #pragma unroll
  for(int j=0;j<12;j++){
    int o = half*192 + j*16 + lc;
    #pragma unroll
    for(int r=0;r<4;r++){
      int s = s0 + w*16 + lr*4 + r;
      float v = acc[j][r];
      if(o < 256){       // q, bug-faithful *sqrt(D)=8 folded in
        int e = o>>6, d = o&63;
        qb[((size_t)((b*NH_+n)*NE_+e)*S_ + s)*D_ + d] = f2bf(v*8.f);
      } else if(o < 320){
        kbf[((size_t)(b*NH_+n)*S_ + s)*D_ + (o-256)] = f2bf(v);
      } else {
        vbf[((size_t)(b*NH_+n)*S_ + s)*D_ + (o-320)] = f2bf(v);
      }
    }
  }
}

// ---- K3: MFMA flash attention; block = (head, pair p) -> q-tiles {p, 15-p} (balanced 17 steps)
__global__ __launch_bounds__(256) void k_attn(const u16* __restrict__ qb, const u16* __restrict__ kb,
        const u16* __restrict__ vb, const float* __restrict__ sx, float* __restrict__ attout){
  int bid = blockIdx.x;
  int head = bid>>3, p = bid&7;
  int bq = head>>2, e = head&3;
  int tid = threadIdx.x, w = tid>>6, l = tid&63, lr = l>>4, lc = l&15;
  __shared__ u16 Ks[2][64*64];
  __shared__ u16 VT[2][64*64];
  __shared__ u16 Pb[4][16*64];
  const u16* kh = kb + (size_t)bq*S_*D_;
  const u16* vh = vb + (size_t)bq*S_*D_;
  const int swl = (lc&7)<<3;
  const int swst = (l&7)<<3;

  #pragma unroll
  for(int ph=0; ph<2; ++ph){
    int qt = ph ? (15-p) : p;
    const u16* qrow = qb + ((size_t)head*S_ + qt*64 + w*16 + lc)*D_;
    bf16x8 qf0 = *(const bf16x8*)(qrow + lr*8);
    bf16x8 qf1 = *(const bf16x8*)(qrow + lr*8 + 32);
    f32x4 Oa[4]; float m_i[4], l_i[4];
    #pragma unroll
    for(int j=0;j<4;j++) Oa[j] = (f32x4){0,0,0,0};
    #pragma unroll
    for(int r=0;r<4;r++){ m_i[r] = -INFINITY; l_i[r] = 0.f; }

    us8 rg[4];
    __syncthreads();
    { const u16* kr = kh + (size_t)l*D_;
      const u16* vr = vh + (size_t)l*D_;
      int c0 = w*8;
      rg[0] = *(const us8*)(kr + c0);      rg[1] = *(const us8*)(kr + c0 + 32);
      rg[2] = *(const us8*)(vr + c0);      rg[3] = *(const us8*)(vr + c0 + 32);
      *(us8*)&Ks[0][l*64 + ( c0      ^ swst)] = rg[0];
      *(us8*)&Ks[0][l*64 + ((c0+32)  ^ swst)] = rg[1];
      #pragma unroll
      for(int i=0;i<8;i++){ int d=c0+i;    VT[0][d*64 + (l ^ ((d&7)<<3))] = rg[2][i]; }
      #pragma unroll
      for(int i=0;i<8;i++){ int d=c0+32+i; VT[0][d*64 + (l ^ ((d&7)<<3))] = rg[3][i]; }
    }
    for(int kt=0; kt<=qt; ++kt){
      int cur = kt&1;
      __syncthreads();
      bool more = kt < qt;
      if(more){
        const u16* kr = kh + ((size_t)(kt+1)*64 + l)*D_;
        const u16* vr = vh + ((size_t)(kt+1)*64 + l)*D_;
        int c0 = w*8;
        rg[0] = *(const us8*)(kr + c0);    rg[1] = *(const us8*)(kr + c0 + 32);
        rg[2] = *(const us8*)(vr + c0);    rg[3] = *(const us8*)(vr + c0 + 32);
      }
      f32x4 Sa[4];
      #pragma unroll
      for(int j=0;j<4;j++){
        const u16* kr = &Ks[cur][(j*16+lc)*64];
        bf16x8 b0 = *(const bf16x8*)(kr + ((lr*8   ) ^ swl));
        bf16x8 b1 = *(const bf16x8*)(kr + ((lr*8+32) ^ swl));
        f32x4 z = (f32x4){0,0,0,0};
        z = MFMA16(qf0,b0,z);
        z = MFMA16(qf1,b1,z);
        Sa[j] = z;
      }
      #pragma unroll
      for(int r=0;r<4;r++){
        int qr = w*16 + lr*4 + r;
        float sv[4];
        #pragma unroll
        for(int j=0;j<4;j++){
          sv[j] = Sa[j][r];
          if(kt==qt && (j*16+lc) > qr) sv[j] = -INFINITY;
        }
        float mx = fmaxf(fmaxf(sv[0],sv[1]),fmaxf(sv[2],sv[3]));
        #pragma unroll
        for(int off=1; off<16; off<<=1) mx = fmaxf(mx, __shfl_xor(mx,off));
        float mn = fmaxf(m_i[r], mx);
        float sc = __expf(m_i[r]-mn);
        float rs = 0.f;
        #pragma unroll
        for(int j=0;j<4;j++){ sv[j] = __expf(sv[j]-mn); rs += sv[j]; }
        #pragma unroll
        for(int off=1; off<16; off<<=1) rs += __shfl_xor(rs,off);
        l_i[r] = l_i[r]*sc + rs;
        m_i[r] = mn;
        #pragma unroll
        for(int j=0;j<4;j++) Oa[j][r] *= sc;
        int prow = lr*4+r, psw = (prow&7)<<3;
        #pragma unroll
        for(int j=0;j<4;j++) Pb[w][prow*64 + ((j*16+lc) ^ psw)] = f2bf(sv[j]);
      }
      asm volatile("s_waitcnt lgkmcnt(0)" ::: "memory");
      bf16x8 pA0 = *(const bf16x8*)&Pb[w][lc*64 + ((lr*8   ) ^ swl)];
      bf16x8 pA1 = *(const bf16x8*)&Pb[w][lc*64 + ((lr*8+32) ^ swl)];
      #pragma unroll
      for(int jd=0;jd<4;jd++){
        const u16* vr = &VT[cur][(jd*16+lc)*64];
        bf16x8 v0 = *(const bf16x8*)(vr + ((lr*8   ) ^ swl));
        bf16x8 v1 = *(const bf16x8*)(vr + ((lr*8+32) ^ swl));
        Oa[jd] = MFMA16(pA0,v0,Oa[jd]);
        Oa[jd] = MFMA16(pA1,v1,Oa[jd]);
      }
      if(more){
        int nb = cur^1, c0 = w*8;
        *(us8*)&Ks[nb][l*64 + ( c0     ^ swst)] = rg[0];
        *(us8*)&Ks[nb][l*64 + ((c0+32) ^ swst)] = rg[1];
        #pragma unroll
        for(int i=0;i<8;i++){ int d=c0+i;    VT[nb][d*64 + (l ^ ((d&7)<<3))] = rg[2][i]; }
        #pragma unroll
        for(int i=0;i<8;i++){ int d=c0+32+i; VT[nb][d*64 + (l ^ ((d&7)<<3))] = rg[3][i]; }
      }
    }
    #pragma unroll
    for(int r=0;r<4;r++){
      int qg = qt*64 + w*16 + lr*4 + r;
      float inv = 1.f/l_i[r];
      #pragma unroll
      for(int jd=0;jd<4;jd++){
        int d = jd*16 + lc;
        float o = Oa[jd][r]*inv;
        if(sx[((size_t)bq*S_ + qg)*D_ + d] == 0.f) o = 0.f;
        attout[((size_t)bq*S_ + qg)*(NE_*D_) + e*D_ + d] = o;
      }
    }
  }
}

// ---- K4 (fused tail): gates+mix+LN1 (VALU, 16-lane reduces) then FFN (MFMA) + LN2 + head-gate
// block = 16 (b,s) rows x all 4 heads; 256 blocks, 256 threads
__global__ __launch_bounds__(256) void k_tail(const float* __restrict__ attout, const float* __restrict__ gw,
      const float* __restrict__ gb, const float* __restrict__ sx,
      const float* __restrict__ lng, const float* __restrict__ lnb,
      const float* __restrict__ w1g, const float* __restrict__ b1g,
      const float* __restrict__ w2g, const float* __restrict__ b2g,
      const float* __restrict__ fng, const float* __restrict__ fnb,
      const float* __restrict__ fgw, float* __restrict__ out){
  int bid = blockIdx.x;
  int gs0 = bid*16, b = gs0>>10, s0 = gs0&1023;
  int tid = threadIdx.x;
  int row = tid>>4, l16 = tid&15;                       // phase-A mapping
  int w = tid>>6, l = tid&63, lr = l>>4, lc = l&15;     // phase-B mapping
  __shared__ float Fx[64][64];     // fn f32 (head-row, d) for mask+residual
  __shared__ u16 FnB[64*64];       // fn bf16 swizzled (GEMM A)
  __shared__ u16 W1[64*64], W2[64*64], H1[64*64];
  __shared__ float Red[4][16][4];  // per-wave fgate partials

  // stage fc1/fc2 (f32 -> bf16, swizzled)
  #pragma unroll
  for(int g2=0; g2<2; ++g2){
    int g = tid*2+g2; int r2 = g>>3, c0 = (g&7)*8;
    float4 a = *(const float4*)(w1g + r2*64 + c0), bb = *(const float4*)(w1g + r2*64 + c0 + 4);
    *(us8*)&W1[r2*64 + (c0 ^ ((r2&7)<<3))] = pack8(a,bb);
    a = *(const float4*)(w2g + r2*64 + c0); bb = *(const float4*)(w2g + r2*64 + c0 + 4);
    *(us8*)&W2[r2*64 + (c0 ^ ((r2&7)<<3))] = pack8(a,bb);
  }
  const int d0 = l16*4;
  // ---- phase A: per head, all in registers + 16-lane reduces
  for(int n=0;n<NH_;++n){
    f32x4 o[4];
    const float* ar = attout + ((size_t)(b*NH_+n)*S_ + s0 + row)*(NE_*D_);
    #pragma unroll
    for(int e=0;e<4;e++) o[e] = *(const f32x4*)(ar + e*64 + d0);
    float lg4[4];
    #pragma unroll
    for(int eg=0; eg<4; ++eg){
      const float* gr = gw + (size_t)(n*NE_+eg)*(NE_*D_);
      float p = 0.f;
      #pragma unroll
      for(int e=0;e<4;e++){
        f32x4 g4 = *(const f32x4*)(gr + e*64 + d0);
        p += o[e][0]*g4[0] + o[e][1]*g4[1] + o[e][2]*g4[2] + o[e][3]*g4[3];
      }
      #pragma unroll
      for(int off=1; off<16; off<<=1) p += __shfl_xor(p, off);
      lg4[eg] = p + gb[n*NE_+eg];
    }
    float mx = fmaxf(fmaxf(lg4[0],lg4[1]),fmaxf(lg4[2],lg4[3]));
    float se = 0.f;
    #pragma unroll
    for(int eg=0;eg<4;eg++){ lg4[eg]=__expf(lg4[eg]-mx); se+=lg4[eg]; }
    float inv = 1.f/se;
    f32x4 res = *(const f32x4*)(sx + ((size_t)(n*NH_+n)*S_ + s0 + row)*D_ + d0);  // bug-faithful resid
    float tv[4];
    #pragma unroll
    for(int k=0;k<4;k++){
      float mixk = o[0][k]*lg4[0] + o[1][k]*lg4[1] + o[2][k]*lg4[2] + o[3][k]*lg4[3];
      tv[k] = mixk*inv + res[k];
    }
    float sum = tv[0]+tv[1]+tv[2]+tv[3];
    #pragma unroll
    for(int off=1; off<16; off<<=1) sum += __shfl_xor(sum, off);
    float mean = sum*(1.f/64.f);
    float vs = 0.f;
    #pragma unroll
    for(int k=0;k<4;k++){ float d = tv[k]-mean; vs += d*d; }
    #pragma unroll
    for(int off=1; off<16; off<<=1) vs += __shfl_xor(vs, off);
    float rstd = rsqrtf(vs*(1.f/64.f)+EPS_);
    f32x4 lgv = *(const f32x4*)(lng + d0);
    f32x4 lbv = *(const f32x4*)(lnb + d0);
    int hr = n*16+row;
    us4 pk;
    f32x4 yv;
    #pragma unroll
    for(int k=0;k<4;k++){
      float y = (tv[k]-mean)*rstd*lgv[k] + lbv[k];
      yv[k] = y; pk[k] = f2bf(y);
    }
    *(f32x4*)&Fx[hr][d0] = yv;
    *(us4*)&FnB[hr*64 + (d0 ^ ((hr&7)<<3))] = pk;
  }
  __syncthreads();
  // ---- phase B: FFN GEMM1 (MFMA), wave w = head w, rows lr*4+rr
  const int swl = (lc&7)<<3;
  bf16x8 a0 = *(const bf16x8*)&FnB[(w*16+lc)*64 + ((lr*8   ) ^ swl)];
  bf16x8 a1 = *(const bf16x8*)&FnB[(w*16+lc)*64 + ((lr*8+32) ^ swl)];
  f32x4 acc1[4];
  #pragma unroll
  for(int jn=0;jn<4;jn++) acc1[jn] = (f32x4){0,0,0,0};
  #pragma unroll
  for(int jn=0;jn<4;jn++){
    const u16* wr = &W1[(jn*16+lc)*64];
    bf16x8 b0 = *(const bf16x8*)(wr + ((lr*8   ) ^ swl));
    bf16x8 b1 = *(const bf16x8*)(wr + ((lr*8+32) ^ swl));
    acc1[jn] = MFMA16(a0,b0,acc1[jn]);
    acc1[jn] = MFMA16(a1,b1,acc1[jn]);
  }
  #pragma unroll
  for(int jn=0;jn<4;jn++){
    int dout = jn*16+lc;
    float bias = b1g[dout];
    #pragma unroll
    for(int rr=0;rr<4;rr++){
      int hr = w*16 + lr*4 + rr;
      float v = acc1[jn][rr] + bias;
      v = (Fx[hr][dout]==0.f) ? 0.f : v;   // bug-faithful pm mask
      v = fmaxf(v, 0.f);
      H1[hr*64 + (dout ^ ((hr&7)<<3))] = f2bf(v);
    }
  }
  __syncthreads();
  // GEMM2
  a0 = *(const bf16x8*)&H1[(w*16+lc)*64 + ((lr*8   ) ^ swl)];
  a1 = *(const bf16x8*)&H1[(w*16+lc)*64 + ((lr*8+32) ^ swl)];
  f32x4 acc2[4];
  #pragma unroll
  for(int jn=0;jn<4;jn++) acc2[jn] = (f32x4){0,0,0,0};
  #pragma unroll
  for(int jn=0;jn<4;jn++){
    const u16* wr = &W2[(jn*16+lc)*64];
    bf16x8 b0 = *(const bf16x8*)(wr + ((lr*8   ) ^ swl));
    bf16x8 b1 = *(const bf16x8*)(wr + ((lr*8+32) ^ swl));
    acc2[jn] = MFMA16(a0,b0,acc2[jn]);
    acc2[jn] = MFMA16(a1,b1,acc2[jn]);
  }
  float tv2[4][4];   // [jn][rr] = h2 + fx
  #pragma unroll
  for(int jn=0;jn<4;jn++){
    int dout = jn*16+lc;
    float bias = b2g[dout];
    #pragma unroll
    for(int rr=0;rr<4;rr++){
      int hr = w*16 + lr*4 + rr;
      float fx = Fx[hr][dout];
      float v = acc2[jn][rr] + bias;
      v = (fx==0.f) ? 0.f : v;
      tv2[jn][rr] = v + fx;
    }
  }
  // LN2 per row (reduce over lc lanes)
  float sum_r[4], vs_r[4];
  #pragma unroll
  for(int rr=0;rr<4;rr++) sum_r[rr] = tv2[0][rr]+tv2[1][rr]+tv2[2][rr]+tv2[3][rr];
  #pragma unroll
  for(int off=1; off<16; off<<=1)
    #pragma unroll
    for(int rr=0;rr<4;rr++) sum_r[rr] += __shfl_xor(sum_r[rr], off);
  float mean_r[4];
  #pragma unroll
  for(int rr=0;rr<4;rr++) mean_r[rr] = sum_r[rr]*(1.f/64.f);
  #pragma unroll
  for(int rr=0;rr<4;rr++){
    float a = tv2[0][rr]-mean_r[rr], b2v = tv2[1][rr]-mean_r[rr];
    float c = tv2[2][rr]-mean_r[rr], d = tv2[3][rr]-mean_r[rr];
    vs_r[rr] = a*a + b2v*b2v + c*c + d*d;
  }
  #pragma unroll
  for(int off=1; off<16; off<<=1)
    #pragma unroll
    for(int rr=0;rr<4;rr++) vs_r[rr] += __shfl_xor(vs_r[rr], off);
  float y2[4][4];
  #pragma unroll
  for(int jn=0;jn<4;jn++){
    int dout = jn*16+lc;
    float g = fng[dout], bb = fnb[dout];
    #pragma unroll
    for(int rr=0;rr<4;rr++){
      float rstd = rsqrtf(vs_r[rr]*(1.f/64.f)+EPS_);
      y2[jn][rr] = (tv2[jn][rr]-mean_r[rr])*rstd*g + bb;
    }
  }
  // fgate partials: p[j] over this head's 64 feats
  float fg4[4][4];   // [j][jn]
  #pragma unroll
  for(int j=0;j<4;j++)
    #pragma unroll
    for(int jn=0;jn<4;jn++)
      fg4[j][jn] = fgw[(size_t)j*H_ + w*64 + jn*16 + lc];
  float pj[4][4];    // [j][rr]
  #pragma unroll
  for(int j=0;j<4;j++)
    #pragma unroll
    for(int rr=0;rr<4;rr++)
      pj[j][rr] = y2[0][rr]*fg4[j][0] + y2[1][rr]*fg4[j][1] + y2[2][rr]*fg4[j][2] + y2[3][rr]*fg4[j][3];
  #pragma unroll
  for(int off=1; off<16; off<<=1)
    #pragma unroll
    for(int j=0;j<4;j++)
      #pragma unroll
      for(int rr=0;rr<4;rr++) pj[j][rr] += __shfl_xor(pj[j][rr], off);
  if(lc==0){
    #pragma unroll
    for(int rr=0;rr<4;rr++)
      #pragma unroll
      for(int j=0;j<4;j++) Red[w][lr*4+rr][j] = pj[j][rr];
  }
  __syncthreads();
  #pragma unroll
  for(int rr=0;rr<4;rr++){
    int srow = lr*4+rr;
    float lgf[4];
    #pragma unroll
    for(int j=0;j<4;j++) lgf[j] = Red[0][srow][j]+Red[1][srow][j]+Red[2][srow][j]+Red[3][srow][j];
    float mx2 = fmaxf(fmaxf(lgf[0],lgf[1]),fmaxf(lgf[2],lgf[3]));
    float se2 = 0.f;
    #pragma unroll
    for(int j=0;j<4;j++){ lgf[j]=__expf(lgf[j]-mx2); se2+=lgf[j]; }
    float gsn = lgf[w]/se2;
    float* op = out + ((size_t)(gs0 + srow))*H_ + w*64;
    #pragma unroll
    for(int jn=0;jn<4;jn++) op[jn*16+lc] = y2[jn][rr]*gsn;
  }
}

extern "C" void kernel_launch(void* const* d_in, const int* in_sizes, int n_in,
                              void* d_out, int out_size, void* d_ws, size_t ws_size,
                              hipStream_t stream){
  const float* x      = (const float*)d_in[0];
  const float* hl_w   = (const float*)d_in[1];
  const float* hl_b   = (const float*)d_in[2];
  const float* wq     = (const float*)d_in[3];
  const float* wk     = (const float*)d_in[4];
  const float* wv     = (const float*)d_in[5];
  const float* gate_w = (const float*)d_in[6];
  const float* gate_b = (const float*)d_in[7];
  const float* ln_g   = (const float*)d_in[8];
  const float* ln_b   = (const float*)d_in[9];
  const float* fc1_w  = (const float*)d_in[10];
  const float* fc1_b  = (const float*)d_in[11];
  const float* fc2_w  = (const float*)d_in[12];
  const float* fc2_b  = (const float*)d_in[13];
  const float* fnorm_g= (const float*)d_in[14];
  const float* fnorm_b= (const float*)d_in[15];
  const float* fgate_w= (const float*)d_in[16];

  const size_t NSD = (size_t)B_*NH_*S_*D_;       // 1M
  float* ws     = (float*)d_ws;
  float* sx     = ws;                            // 1M f32
  float* attout = sx + NSD;                      // 4M f32
  float* f_n    = attout + NSD*NE_;              // (unused, kept for layout)
  u16*   sxb    = (u16*)(f_n + NSD);             // 1M u16
  u16*   qb     = sxb + NSD;                     // 4M u16
  u16*   kbf    = qb + NSD*NE_;                  // 1M u16
  u16*   vbf    = kbf + NSD;                     // 1M u16

  k_sx  <<<512,  256, 0, stream>>>(x, hl_w, hl_b, sx, sxb);
  k_qkv <<<512,  256, 0, stream>>>(sxb, wq, wk, wv, qb, kbf, vbf);
  k_attn<<<512,  256, 0, stream>>>(qb, kbf, vbf, sx, attout);
  k_tail<<<256,  256, 0, stream>>>(attout, gate_w, gate_b, sx, ln_g, ln_b,
                                   fc1_w, fc1_b, fc2_w, fc2_b,
                                   fnorm_g, fnorm_b, fgate_w, (float*)d_out);
}

// Round 5
// 67.062 us; speedup vs baseline: 9.9321x; 1.1033x over previous
//
#include <hip/hip_runtime.h>
#include <math.h>

typedef unsigned short u16;
typedef __attribute__((ext_vector_type(8))) unsigned short us8;
typedef __attribute__((ext_vector_type(4))) unsigned short us4;
typedef __attribute__((ext_vector_type(8))) short bf16x8;   // MFMA A/B frag (8 bf16, 4 VGPR)
typedef __attribute__((ext_vector_type(4))) float f32x4;    // MFMA C/D frag

constexpr int B_ = 4, S_ = 1024, H_ = 256, NH_ = 4, NE_ = 4, D_ = 64;
constexpr float EPS_ = 1e-8f;

__device__ __forceinline__ u16 f2bf(float f){
  unsigned u = __float_as_uint(f);
  unsigned rnd = 0x7fffu + ((u>>16)&1u);
  return (u16)((u + rnd)>>16);
}
__device__ __forceinline__ us8 pack8(float4 a, float4 b){
  us8 r;
  r[0]=f2bf(a.x); r[1]=f2bf(a.y); r[2]=f2bf(a.z); r[3]=f2bf(a.w);
  r[4]=f2bf(b.x); r[5]=f2bf(b.y); r[6]=f2bf(b.z); r[7]=f2bf(b.w);
  return r;
}
#define MFMA16(a,b,c) __builtin_amdgcn_mfma_f32_16x16x32_bf16((bf16x8)(a),(bf16x8)(b),(c),0,0,0)

// ---- K1: sx = x . hl_w^T + hl_b  (MFMA GEMM M=4096 N=256 K=256; BM=64 BN=32 BK=64)
__global__ __launch_bounds__(256) void k_sx(const float* __restrict__ x, const float* __restrict__ hlw,
                                            const float* __restrict__ hlb,
                                            float* __restrict__ sx, u16* __restrict__ sxb){
  int mt = blockIdx.x >> 3, nt = blockIdx.x & 7;
  int tid = threadIdx.x, w = tid>>6, l = tid&63, lr = l>>4, lc = l&15;
  __shared__ u16 Xs[64*64];
  __shared__ u16 Ws[32*64];
  const int swl = (lc&7)<<3;
  f32x4 acc[2] = {{0,0,0,0},{0,0,0,0}};
  for(int ks=0; ks<4; ++ks){
    __syncthreads();
    #pragma unroll
    for(int it=0; it<2; ++it){
      int c0 = w*8 + it*32;
      const float* xp = x + ((size_t)(mt*64+l))*H_ + ks*64 + c0;
      float4 a = *(const float4*)xp, b = *(const float4*)(xp+4);
      *(us8*)&Xs[l*64 + (c0 ^ ((l&7)<<3))] = pack8(a,b);
    }
    { int row = tid&31, c0 = (tid>>5)*8;
      const float* wp = hlw + ((size_t)(nt*32+row))*H_ + ks*64 + c0;
      float4 a = *(const float4*)wp, b = *(const float4*)(wp+4);
      *(us8*)&Ws[row*64 + (c0 ^ ((row&7)<<3))] = pack8(a,b);
    }
    __syncthreads();
    bf16x8 a0 = *(const bf16x8*)&Xs[(w*16+lc)*64 + ((lr*8   ) ^ swl)];
    bf16x8 a1 = *(const bf16x8*)&Xs[(w*16+lc)*64 + ((lr*8+32) ^ swl)];
    #pragma unroll
    for(int j=0;j<2;j++){
      const u16* wr = &Ws[(j*16+lc)*64];
      bf16x8 b0 = *(const bf16x8*)(wr + ((lr*8   ) ^ swl));
      bf16x8 b1 = *(const bf16x8*)(wr + ((lr*8+32) ^ swl));
      acc[j] = MFMA16(a0,b0,acc[j]);
      acc[j] = MFMA16(a1,b1,acc[j]);
    }
  }
  #pragma unroll
  for(int j=0;j<2;j++){
    int col = nt*32 + j*16 + lc;
    int n = col>>6, d = col&63;
    float bias = hlb[col];
    #pragma unroll
    for(int r=0;r<4;r++){
      int m = mt*64 + w*16 + lr*4 + r;
      int b = m>>10, s = m&1023;
      float v = acc[j][r] + bias;
      size_t idx = ((size_t)(b*NH_+n)*S_+s)*D_ + d;
      sx[idx] = v; sxb[idx] = f2bf(v);
    }
  }
}

// ---- K2: q/k/v projections per head (MFMA; N=384 split in halves of 192)
__global__ __launch_bounds__(256) void k_qkv(const u16* __restrict__ sxb, const float* __restrict__ wq,
            const float* __restrict__ wk, const float* __restrict__ wv,
            u16* __restrict__ qb, u16* __restrict__ kbf, u16* __restrict__ vbf){
  int bid = blockIdx.x;
  int half = bid&1, mt = (bid>>1)&63, n = bid>>7;
  int tid = threadIdx.x, w = tid>>6, l = tid&63, lr = l>>4, lc = l&15;
  __shared__ u16 As[64*64];
  __shared__ u16 Ws[192*64];
  const int swl = (lc&7)<<3;
  int b = (mt*64)>>10, s0 = (mt*64)&1023;
  #pragma unroll
  for(int it=0; it<2; ++it){
    int c0 = w*8 + it*32;
    us8 v = *(const us8*)(sxb + ((size_t)(b*NH_+n)*S_ + s0 + l)*D_ + c0);
    *(us8*)&As[l*64 + (c0 ^ ((l&7)<<3))] = v;
  }
  #pragma unroll
  for(int ch=0; ch<3; ++ch){
    int o = half*192 + ch*64 + l;
    const float* src;
    if(o < 256)      src = wq + ((size_t)((n*NE_ + (o>>6))*D_ + (o&63)))*D_;
    else if(o < 320) src = wk + ((size_t)(n*D_ + (o-256)))*D_;
    else             src = wv + ((size_t)(n*D_ + (o-320)))*D_;
    #pragma unroll
    for(int it=0; it<2; ++it){
      int c0 = w*8 + it*32;
      float4 a = *(const float4*)(src+c0), bb = *(const float4*)(src+c0+4);
      *(us8*)&Ws[(ch*64+l)*64 + (c0 ^ ((l&7)<<3))] = pack8(a,bb);
    }
  }
  __syncthreads();
  bf16x8 a0 = *(const bf16x8*)&As[(w*16+lc)*64 + ((lr*8   ) ^ swl)];
  bf16x8 a1 = *(const bf16x8*)&As[(w*16+lc)*64 + ((lr*8+32) ^ swl)];
  f32x4 acc[12];
  #pragma unroll
  for(int j=0;j<12;j++) acc[j] = (f32x4){0,0,0,0};
  #pragma unroll
  for(int j=0;j<12;j++){
    const u16* wr = &Ws[(j*16+lc)*64];
    bf16x8 b0 = *(const bf16x8*)(wr + ((lr*8   ) ^ swl));
    bf16x8 b1 = *(const bf16x8*)(wr + ((lr*8+32) ^ swl));
    acc[j] = MFMA16(a0,b0,acc[j]);
    acc[j] = MFMA16(a1,b1,acc[j]);
  }
  #pragma unroll
  for(int j=0;j<12;j++){
    int o = half*192 + j*16 + lc;
    #pragma unroll
    for(int r=0;r<4;r++){
      int s = s0 + w*16 + lr*4 + r;
      float v = acc[j][r];
      if(o < 256){       // q: bug-faithful *sqrt(D)=8, plus log2e for exp2-domain softmax
        int e = o>>6, d = o&63;
        qb[((size_t)((b*NH_+n)*NE_+e)*S_ + s)*D_ + d] = f2bf(v*11.5415603f);
      } else if(o < 320){
        kbf[((size_t)(b*NH_+n)*S_ + s)*D_ + (o-256)] = f2bf(v);
      } else {
        vbf[((size_t)(b*NH_+n)*S_ + s)*D_ + (o-320)] = f2bf(v);
      }
    }
  }
}

// ---- K3 v2: swapped-operand MFMA flash attention (S^T and O^T), log2-domain softmax.
// block = (head, one 64-row q-tile); grid 1024 (4 blocks/CU); stride-4-balanced qt permutation.
__global__ __launch_bounds__(256,4) void k_attn(const u16* __restrict__ qb, const u16* __restrict__ kb,
        const u16* __restrict__ vb, const float* __restrict__ sx, float* __restrict__ attout){
  int bid = blockIdx.x;
  int head = bid & 63, idx = bid >> 6;
  int g = idx>>2, pos = idx&3;
  int qt = (g&1) ? (15 - (g>>1) - 2*pos) : ((g>>1) + 2*pos);  // classes {i,i+4,i+8,i+12} sum to 30
  int bq = head>>2, e = head&3;
  int tid = threadIdx.x, w = tid>>6, l = tid&63, lr = l>>4, lc = l&15;
  __shared__ u16 Ks[2][64*64];
  __shared__ u16 VT[2][64*64];
  __shared__ u16 Pb[4][16*64];
  const u16* kh = kb + (size_t)bq*S_*D_;
  const u16* vh = vb + (size_t)bq*S_*D_;
  const int swl = (lc&7)<<3;           // swizzle for rows indexed by lc
  const int swst = (l&7)<<3;           // staging swizzle (row = l)

  // Q used as MFMA B operand: lane holds Q[row w*16+lc][d = lr*8 + 0..7 (+32)]
  const u16* qrow = qb + ((size_t)head*S_ + qt*64 + w*16 + lc)*D_;
  bf16x8 qf0 = *(const bf16x8*)(qrow + lr*8);
  bf16x8 qf1 = *(const bf16x8*)(qrow + lr*8 + 32);
  f32x4 Oa[4];                         // O^T: lane q=lc, d = jd*16 + lr*4 + reg
  #pragma unroll
  for(int j=0;j<4;j++) Oa[j] = (f32x4){0,0,0,0};
  float m_i = -INFINITY, l_i = 0.f;    // scalar per lane (q = w*16+lc)

  us8 rg[4];
  { // prologue: stage kt=0 into buf 0
    const u16* kr = kh + (size_t)l*D_;
    const u16* vr = vh + (size_t)l*D_;
    int c0 = w*8;
    rg[0] = *(const us8*)(kr + c0);      rg[1] = *(const us8*)(kr + c0 + 32);
    rg[2] = *(const us8*)(vr + c0);      rg[3] = *(const us8*)(vr + c0 + 32);
    *(us8*)&Ks[0][l*64 + ( c0      ^ swst)] = rg[0];
    *(us8*)&Ks[0][l*64 + ((c0+32)  ^ swst)] = rg[1];
    #pragma unroll
    for(int i=0;i<8;i++){ int d=c0+i;    VT[0][d*64 + (l ^ ((d&7)<<3))] = rg[2][i]; }
    #pragma unroll
    for(int i=0;i<8;i++){ int d=c0+32+i; VT[0][d*64 + (l ^ ((d&7)<<3))] = rg[3][i]; }
  }
  for(int kt=0; kt<=qt; ++kt){
    int cur = kt&1;
    __syncthreads();
    bool more = kt < qt;
    if(more){                            // T14: issue next-tile loads before compute
      const u16* kr = kh + ((size_t)(kt+1)*64 + l)*D_;
      const u16* vr = vh + ((size_t)(kt+1)*64 + l)*D_;
      int c0 = w*8;
      rg[0] = *(const us8*)(kr + c0);    rg[1] = *(const us8*)(kr + c0 + 32);
      rg[2] = *(const us8*)(vr + c0);    rg[3] = *(const us8*)(vr + c0 + 32);
    }
    // S^T = K Q^T: lane holds S[k = j*16+lr*4+r][q = w*16+lc]
    f32x4 Sa[4];
    #pragma unroll
    for(int j=0;j<4;j++){
      const u16* kr = &Ks[cur][(j*16+lc)*64];
      bf16x8 a0 = *(const bf16x8*)(kr + ((lr*8   ) ^ swl));
      bf16x8 a1 = *(const bf16x8*)(kr + ((lr*8+32) ^ swl));
      f32x4 z = (f32x4){0,0,0,0};
      z = MFMA16(a0,qf0,z);
      z = MFMA16(a1,qf1,z);
      Sa[j] = z;
    }
    if(kt==qt){                          // causal mask (tile-local: k > q)
      int q = w*16 + lc;
      #pragma unroll
      for(int j=0;j<4;j++)
        #pragma unroll
        for(int r=0;r<4;r++)
          if(j*16 + lr*4 + r > q) Sa[j][r] = -INFINITY;
    }
    // online softmax: in-lane tree + 2 shfl (lanes lr=0..3 share q row)
    float mx0 = fmaxf(fmaxf(Sa[0][0],Sa[0][1]),fmaxf(Sa[0][2],Sa[0][3]));
    float mx1 = fmaxf(fmaxf(Sa[1][0],Sa[1][1]),fmaxf(Sa[1][2],Sa[1][3]));
    float mx2 = fmaxf(fmaxf(Sa[2][0],Sa[2][1]),fmaxf(Sa[2][2],Sa[2][3]));
    float mx3 = fmaxf(fmaxf(Sa[3][0],Sa[3][1]),fmaxf(Sa[3][2],Sa[3][3]));
    float mx = fmaxf(fmaxf(mx0,mx1),fmaxf(mx2,mx3));
    mx = fmaxf(mx, __shfl_xor(mx,16));
    mx = fmaxf(mx, __shfl_xor(mx,32));
    float mn = fmaxf(m_i, mx);
    float scale = exp2f(m_i - mn);       // exp2(-inf)=0 on first tile
    #pragma unroll
    for(int j=0;j<4;j++)
      #pragma unroll
      for(int r=0;r<4;r++) Sa[j][r] = exp2f(Sa[j][r] - mn);
    float rs0 = (Sa[0][0]+Sa[0][1]) + (Sa[0][2]+Sa[0][3]);
    float rs1 = (Sa[1][0]+Sa[1][1]) + (Sa[1][2]+Sa[1][3]);
    float rs2 = (Sa[2][0]+Sa[2][1]) + (Sa[2][2]+Sa[2][3]);
    float rs3 = (Sa[3][0]+Sa[3][1]) + (Sa[3][2]+Sa[3][3]);
    float rs = (rs0+rs1) + (rs2+rs3);
    rs += __shfl_xor(rs,16);
    rs += __shfl_xor(rs,32);
    l_i = l_i*scale + rs;
    m_i = mn;
    #pragma unroll
    for(int jd=0;jd<4;jd++)
      #pragma unroll
      for(int r=0;r<4;r++) Oa[jd][r] *= scale;
    // P store: packed b64 per j (row q=lc, cols j*16+lr*4 .. +3, contiguous)
    #pragma unroll
    for(int j=0;j<4;j++){
      us4 pk;
      #pragma unroll
      for(int r=0;r<4;r++) pk[r] = f2bf(Sa[j][r]);
      *(us4*)&Pb[w][lc*64 + ((j*16+lr*4) ^ swl)] = pk;
    }
    asm volatile("s_waitcnt lgkmcnt(0)" ::: "memory");
    // P as B operand: lane needs P[q=lc][kv = lr*8 + 0..7 (+32)]
    bf16x8 pB0 = *(const bf16x8*)&Pb[w][lc*64 + ((lr*8   ) ^ swl)];
    bf16x8 pB1 = *(const bf16x8*)&Pb[w][lc*64 + ((lr*8+32) ^ swl)];
    // O^T += V^T P^T
    #pragma unroll
    for(int jd=0;jd<4;jd++){
      const u16* vr = &VT[cur][(jd*16+lc)*64];
      bf16x8 v0 = *(const bf16x8*)(vr + ((lr*8   ) ^ swl));
      bf16x8 v1 = *(const bf16x8*)(vr + ((lr*8+32) ^ swl));
      Oa[jd] = MFMA16(v0,pB0,Oa[jd]);
      Oa[jd] = MFMA16(v1,pB1,Oa[jd]);
    }
    if(more){                            // write next tile into other buffer
      int nb = cur^1, c0 = w*8;
      *(us8*)&Ks[nb][l*64 + ( c0     ^ swst)] = rg[0];
      *(us8*)&Ks[nb][l*64 + ((c0+32) ^ swst)] = rg[1];
      #pragma unroll
      for(int i=0;i<8;i++){ int d=c0+i;    VT[nb][d*64 + (l ^ ((d&7)<<3))] = rg[2][i]; }
      #pragma unroll
      for(int i=0;i<8;i++){ int d=c0+32+i; VT[nb][d*64 + (l ^ ((d&7)<<3))] = rg[3][i]; }
    }
  }
  // epilogue: lane owns one q row; vectorized mask + store
  int qg = qt*64 + w*16 + lc;
  float inv = 1.f/l_i;
  const float* sxp = sx + ((size_t)bq*S_ + qg)*D_;
  float* op = attout + ((size_t)bq*S_ + qg)*(NE_*D_) + e*D_;
  #pragma unroll
  for(int jd=0;jd<4;jd++){
    int d0 = jd*16 + lr*4;
    f32x4 sxv = *(const f32x4*)(sxp + d0);
    f32x4 ov;
    #pragma unroll
    for(int r=0;r<4;r++){
      float o = Oa[jd][r]*inv;
      ov[r] = (sxv[r]==0.f) ? 0.f : o;   // bug-faithful pad mask
    }
    *(f32x4*)(op + d0) = ov;
  }
}

// ---- K4 (fused tail): gates+mix+LN1 (VALU, 16-lane reduces) then FFN (MFMA) + LN2 + head-gate
__global__ __launch_bounds__(256) void k_tail(const float* __restrict__ attout, const float* __restrict__ gw,
      const float* __restrict__ gb, const float* __restrict__ sx,
      const float* __restrict__ lng, const float* __restrict__ lnb,
      const float* __restrict__ w1g, const float* __restrict__ b1g,
      const float* __restrict__ w2g, const float* __restrict__ b2g,
      const float* __restrict__ fng, const float* __restrict__ fnb,
      const float* __restrict__ fgw, float* __restrict__ out){
  int bid = blockIdx.x;
  int gs0 = bid*16, b = gs0>>10, s0 = gs0&1023;
  int tid = threadIdx.x;
  int row = tid>>4, l16 = tid&15;
  int w = tid>>6, l = tid&63, lr = l>>4, lc = l&15;
  __shared__ float Fx[64][64];
  __shared__ u16 FnB[64*64];
  __shared__ u16 W1[64*64], W2[64*64], H1[64*64];
  __shared__ float Red[4][16][4];

  #pragma unroll
  for(int g2=0; g2<2; ++g2){
    int g = tid*2+g2; int r2 = g>>3, c0 = (g&7)*8;
    float4 a = *(const float4*)(w1g + r2*64 + c0), bb = *(const float4*)(w1g + r2*64 + c0 + 4);
    *(us8*)&W1[r2*64 + (c0 ^ ((r2&7)<<3))] = pack8(a,bb);
    a = *(const float4*)(w2g + r2*64 + c0); bb = *(const float4*)(w2g + r2*64 + c0 + 4);
    *(us8*)&W2[r2*64 + (c0 ^ ((r2&7)<<3))] = pack8(a,bb);
  }
  const int d0 = l16*4;
  for(int n=0;n<NH_;++n){
    f32x4 o[4];
    const float* ar = attout + ((size_t)(b*NH_+n)*S_ + s0 + row)*(NE_*D_);
    #pragma unroll
    for(int e=0;e<4;e++) o[e] = *(const f32x4*)(ar + e*64 + d0);
    float lg4[4];
    #pragma unroll
    for(int eg=0; eg<4; ++eg){
      const float* gr = gw + (size_t)(n*NE_+eg)*(NE_*D_);
      float p = 0.f;
      #pragma unroll
      for(int e=0;e<4;e++){
        f32x4 g4 = *(const f32x4*)(gr + e*64 + d0);
        p += o[e][0]*g4[0] + o[e][1]*g4[1] + o[e][2]*g4[2] + o[e][3]*g4[3];
      }
      #pragma unroll
      for(int off=1; off<16; off<<=1) p += __shfl_xor(p, off);
      lg4[eg] = p + gb[n*NE_+eg];
    }
    float mx = fmaxf(fmaxf(lg4[0],lg4[1]),fmaxf(lg4[2],lg4[3]));
    float se = 0.f;
    #pragma unroll
    for(int eg=0;eg<4;eg++){ lg4[eg]=__expf(lg4[eg]-mx); se+=lg4[eg]; }
    float inv = 1.f/se;
    f32x4 res = *(const f32x4*)(sx + ((size_t)(n*NH_+n)*S_ + s0 + row)*D_ + d0);
    float tv[4];
    #pragma unroll
    for(int k=0;k<4;k++){
      float mixk = o[0][k]*lg4[0] + o[1][k]*lg4[1] + o[2][k]*lg4[2] + o[3][k]*lg4[3];
      tv[k] = mixk*inv + res[k];
    }
    float sum = tv[0]+tv[1]+tv[2]+tv[3];
    #pragma unroll
    for(int off=1; off<16; off<<=1) sum += __shfl_xor(sum, off);
    float mean = sum*(1.f/64.f);
    float vs = 0.f;
    #pragma unroll
    for(int k=0;k<4;k++){ float d = tv[k]-mean; vs += d*d; }
    #pragma unroll
    for(int off=1; off<16; off<<=1) vs += __shfl_xor(vs, off);
    float rstd = rsqrtf(vs*(1.f/64.f)+EPS_);
    f32x4 lgv = *(const f32x4*)(lng + d0);
    f32x4 lbv = *(const f32x4*)(lnb + d0);
    int hr = n*16+row;
    us4 pk;
    f32x4 yv;
    #pragma unroll
    for(int k=0;k<4;k++){
      float y = (tv[k]-mean)*rstd*lgv[k] + lbv[k];
      yv[k] = y; pk[k] = f2bf(y);
    }
    *(f32x4*)&Fx[hr][d0] = yv;
    *(us4*)&FnB[hr*64 + (d0 ^ ((hr&7)<<3))] = pk;
  }
  __syncthreads();
  const int swl = (lc&7)<<3;
  bf16x8 a0 = *(const bf16x8*)&FnB[(w*16+lc)*64 + ((lr*8   ) ^ swl)];
  bf16x8 a1 = *(const bf16x8*)&FnB[(w*16+lc)*64 + ((lr*8+32) ^ swl)];
  f32x4 acc1[4];
  #pragma unroll
  for(int jn=0;jn<4;jn++) acc1[jn] = (f32x4){0,0,0,0};
  #pragma unroll
  for(int jn=0;jn<4;jn++){
    const u16* wr = &W1[(jn*16+lc)*64];
    bf16x8 b0 = *(const bf16x8*)(wr + ((lr*8   ) ^ swl));
    bf16x8 b1 = *(const bf16x8*)(wr + ((lr*8+32) ^ swl));
    acc1[jn] = MFMA16(a0,b0,acc1[jn]);
    acc1[jn] = MFMA16(a1,b1,acc1[jn]);
  }
  #pragma unroll
  for(int jn=0;jn<4;jn++){
    int dout = jn*16+lc;
    float bias = b1g[dout];
    #pragma unroll
    for(int rr=0;rr<4;rr++){
      int hr = w*16 + lr*4 + rr;
      float v = acc1[jn][rr] + bias;
      v = (Fx[hr][dout]==0.f) ? 0.f : v;
      v = fmaxf(v, 0.f);
      H1[hr*64 + (dout ^ ((hr&7)<<3))] = f2bf(v);
    }
  }
  __syncthreads();
  a0 = *(const bf16x8*)&H1[(w*16+lc)*64 + ((lr*8   ) ^ swl)];
  a1 = *(const bf16x8*)&H1[(w*16+lc)*64 + ((lr*8+32) ^ swl)];
  f32x4 acc2[4];
  #pragma unroll
  for(int jn=0;jn<4;jn++) acc2[jn] = (f32x4){0,0,0,0};
  #pragma unroll
  for(int jn=0;jn<4;jn++){
    const u16* wr = &W2[(jn*16+lc)*64];
    bf16x8 b0 = *(const bf16x8*)(wr + ((lr*8   ) ^ swl));
    bf16x8 b1 = *(const bf16x8*)(wr + ((lr*8+32) ^ swl));
    acc2[jn] = MFMA16(a0,b0,acc2[jn]);
    acc2[jn] = MFMA16(a1,b1,acc2[jn]);
  }
  float tv2[4][4];
  #pragma unroll
  for(int jn=0;jn<4;jn++){
    int dout = jn*16+lc;
    float bias = b2g[dout];
    #pragma unroll
    for(int rr=0;rr<4;rr++){
      int hr = w*16 + lr*4 + rr;
      float fx = Fx[hr][dout];
      float v = acc2[jn][rr] + bias;
      v = (fx==0.f) ? 0.f : v;
      tv2[jn][rr] = v + fx;
    }
  }
  float sum_r[4], vs_r[4];
  #pragma unroll
  for(int rr=0;rr<4;rr++) sum_r[rr] = tv2[0][rr]+tv2[1][rr]+tv2[2][rr]+tv2[3][rr];
  #pragma unroll
  for(int off=1; off<16; off<<=1)
    #pragma unroll
    for(int rr=0;rr<4;rr++) sum_r[rr] += __shfl_xor(sum_r[rr], off);
  float mean_r[4];
  #pragma unroll
  for(int rr=0;rr<4;rr++) mean_r[rr] = sum_r[rr]*(1.f/64.f);
  #pragma unroll
  for(int rr=0;rr<4;rr++){
    float a = tv2[0][rr]-mean_r[rr], b2v = tv2[1][rr]-mean_r[rr];
    float c = tv2[2][rr]-mean_r[rr], d = tv2[3][rr]-mean_r[rr];
    vs_r[rr] = a*a + b2v*b2v + c*c + d*d;
  }
  #pragma unroll
  for(int off=1; off<16; off<<=1)
    #pragma unroll
    for(int rr=0;rr<4;rr++) vs_r[rr] += __shfl_xor(vs_r[rr], off);
  float y2[4][4];
  #pragma unroll
  for(int jn=0;jn<4;jn++){
    int dout = jn*16+lc;
    float g = fng[dout], bb = fnb[dout];
    #pragma unroll
    for(int rr=0;rr<4;rr++){
      float rstd = rsqrtf(vs_r[rr]*(1.f/64.f)+EPS_);
      y2[jn][rr] = (tv2[jn][rr]-mean_r[rr])*rstd*g + bb;
    }
  }
  float fg4[4][4];
  #pragma unroll
  for(int j=0;j<4;j++)
    #pragma unroll
    for(int jn=0;jn<4;jn++)
      fg4[j][jn] = fgw[(size_t)j*H_ + w*64 + jn*16 + lc];
  float pj[4][4];
  #pragma unroll
  for(int j=0;j<4;j++)
    #pragma unroll
    for(int rr=0;rr<4;rr++)
      pj[j][rr] = y2[0][rr]*fg4[j][0] + y2[1][rr]*fg4[j][1] + y2[2][rr]*fg4[j][2] + y2[3][rr]*fg4[j][3];
  #pragma unroll
  for(int off=1; off<16; off<<=1)
    #pragma unroll
    for(int j=0;j<4;j++)
      #pragma unroll
      for(int rr=0;rr<4;rr++) pj[j][rr] += __shfl_xor(pj[j][rr], off);
  if(lc==0){
    #pragma unroll
    for(int rr=0;rr<4;rr++)
      #pragma unroll
      for(int j=0;j<4;j++) Red[w][lr*4+rr][j] = pj[j][rr];
  }
  __syncthreads();
  #pragma unroll
  for(int rr=0;rr<4;rr++){
    int srow = lr*4+rr;
    float lgf[4];
    #pragma unroll
    for(int j=0;j<4;j++) lgf[j] = Red[0][srow][j]+Red[1][srow][j]+Red[2][srow][j]+Red[3][srow][j];
    float mx2 = fmaxf(fmaxf(lgf[0],lgf[1]),fmaxf(lgf[2],lgf[3]));
    float se2 = 0.f;
    #pragma unroll
    for(int j=0;j<4;j++){ lgf[j]=__expf(lgf[j]-mx2); se2+=lgf[j]; }
    float gsn = lgf[w]/se2;
    float* op = out + ((size_t)(gs0 + srow))*H_ + w*64;
    #pragma unroll
    for(int jn=0;jn<4;jn++) op[jn*16+lc] = y2[jn][rr]*gsn;
  }
}

extern "C" void kernel_launch(void* const* d_in, const int* in_sizes, int n_in,
                              void* d_out, int out_size, void* d_ws, size_t ws_size,
                              hipStream_t stream){
  const float* x      = (const float*)d_in[0];
  const float* hl_w   = (const float*)d_in[1];
  const float* hl_b   = (const float*)d_in[2];
  const float* wq     = (const float*)d_in[3];
  const float* wk     = (const float*)d_in[4];
  const float* wv     = (const float*)d_in[5];
  const float* gate_w = (const float*)d_in[6];
  const float* gate_b = (const float*)d_in[7];
  const float* ln_g   = (const float*)d_in[8];
  const float* ln_b   = (const float*)d_in[9];
  const float* fc1_w  = (const float*)d_in[10];
  const float* fc1_b  = (const float*)d_in[11];
  const float* fc2_w  = (const float*)d_in[12];
  const float* fc2_b  = (const float*)d_in[13];
  const float* fnorm_g= (const float*)d_in[14];
  const float* fnorm_b= (const float*)d_in[15];
  const float* fgate_w= (const float*)d_in[16];

  const size_t NSD = (size_t)B_*NH_*S_*D_;       // 1M
  float* ws     = (float*)d_ws;
  float* sx     = ws;                            // 1M f32
  float* attout = sx + NSD;                      // 4M f32
  float* f_n    = attout + NSD*NE_;              // (unused, kept for layout)
  u16*   sxb    = (u16*)(f_n + NSD);             // 1M u16
  u16*   qb     = sxb + NSD;                     // 4M u16
  u16*   kbf    = qb + NSD*NE_;                  // 1M u16
  u16*   vbf    = kbf + NSD;                     // 1M u16

  k_sx  <<<512,  256, 0, stream>>>(x, hl_w, hl_b, sx, sxb);
  k_qkv <<<512,  256, 0, stream>>>(sxb, wq, wk, wv, qb, kbf, vbf);
  k_attn<<<1024, 256, 0, stream>>>(qb, kbf, vbf, sx, attout);
  k_tail<<<256,  256, 0, stream>>>(attout, gate_w, gate_b, sx, ln_g, ln_b,
                                   fc1_w, fc1_b, fc2_w, fc2_b,
                                   fnorm_g, fnorm_b, fgate_w, (float*)d_out);
}